// Round 7
// baseline (237.456 us; speedup 1.0000x reference)
//
#include <hip/hip_runtime.h>

#define NB    4096      // histogram buckets over [0,1)
#define CAP   1024      // per-batch collect capacity (expected ~64 in threshold bucket)
#define BATCH 32
#define NTOK  262144    // 512*512
#define HB    512       // hist blocks (16 per batch)
#define HPB   16
#define LOSS_BLOCKS 2048   // B*NTOK / 16 tokens-per-thread / 256 threads

typedef float floatx4 __attribute__((ext_vector_type(4)));  // nt-load-compatible

__device__ __forceinline__ int bucket_of(float v) {
    int b = (int)(v * (float)NB);
    return b > NB - 1 ? NB - 1 : b;
}

// --- Pass 1: LDS-private histogram, atomic flush into per-batch global hist ---
// 512 blocks x 256 thr. ~2M scatter atomics over 128K addresses: low contention.
__global__ void hist_kernel(const float* __restrict__ smap, int* __restrict__ hist) {
    __shared__ int lh[NB];
    for (int i = threadIdx.x; i < NB; i += 256) lh[i] = 0;
    __syncthreads();
    const int b  = blockIdx.x / HPB;
    const int cb = blockIdx.x % HPB;
    const int chunk = NTOK / HPB;                 // 16384 floats
    const float4* src = (const float4*)(smap + (size_t)b * NTOK + (size_t)cb * chunk);
    for (int i = threadIdx.x; i < chunk / 4; i += 256) {
        float4 v = src[i];
        atomicAdd(&lh[bucket_of(v.x)], 1);
        atomicAdd(&lh[bucket_of(v.y)], 1);
        atomicAdd(&lh[bucket_of(v.z)], 1);
        atomicAdd(&lh[bucket_of(v.w)], 1);
    }
    __syncthreads();
    int* gh = hist + b * NB;
    for (int i = threadIdx.x; i < NB; i += 256) {
        int c = lh[i];
        if (c) atomicAdd(&gh[i], c);
    }
}

// --- Pass 2: suffix-scan per-batch hist (512 KB total), emit (tb, R); zero cnt ---
// 32 blocks x 1024 thr.
__global__ __launch_bounds__(1024) void select_kernel(const int* __restrict__ hist,
                                                      const int* __restrict__ kptr,
                                                      int* __restrict__ tbR,
                                                      int* __restrict__ cnt) {
    __shared__ int h[NB];
    __shared__ int sA[1024];
    __shared__ int sB[1024];
    const int tid = threadIdx.x;
    const int b   = blockIdx.x;
    if (tid == 0) cnt[b] = 0;

    const int C = NB / 1024;  // 4 buckets per thread
    int base = tid * C;
    const int* gh = hist + b * NB;
#pragma unroll
    for (int i = 0; i < C; i++) h[base + i] = gh[base + i];
    int csum = h[base] + h[base + 1] + h[base + 2] + h[base + 3];
    sA[tid] = csum;
    __syncthreads();

    // Hillis-Steele inclusive SUFFIX scan over 1024 chunk sums
    int* pin = sA; int* pout = sB;
    for (int st = 1; st < 1024; st <<= 1) {
        int v = pin[tid] + ((tid + st < 1024) ? pin[tid + st] : 0);
        pout[tid] = v;
        __syncthreads();
        int* t_ = pin; pin = pout; pout = t_;
    }
    int above = (tid < 1023) ? pin[tid + 1] : 0;  // strictly above this chunk

    const int K = *kptr;
    int cum = above;
    for (int i = C - 1; i >= 0; i--) {
        int hb = h[base + i];
        if (cum < K && cum + hb >= K) {
            tbR[2 * b]     = base + i;   // threshold bucket
            tbR[2 * b + 1] = K - cum;    // residual rank R (1..hist[tb])
        }
        cum += hb;
    }
}

// --- Pass 3: collect (value, index) of elements in the threshold bucket ---
// 512 blocks x 256 thr; smap is L3-hot from pass 1.
__global__ void collect_kernel(const float* __restrict__ smap, const int* __restrict__ tbR,
                               int* __restrict__ cnt, float* __restrict__ cval,
                               int* __restrict__ cidx) {
    const int b  = blockIdx.x / HPB;
    const int cb = blockIdx.x % HPB;
    const int chunk = NTOK / HPB;                  // 16384 floats
    const int tb = tbR[2 * b];
    const float4* src = (const float4*)(smap + (size_t)b * NTOK + (size_t)cb * chunk);
    const int base_n = cb * chunk;
    for (int i = threadIdx.x; i < chunk / 4; i += 256) {
        float4 v = src[i];
        float vals[4] = {v.x, v.y, v.z, v.w};
#pragma unroll
        for (int s = 0; s < 4; s++) {
            if (bucket_of(vals[s]) == tb) {
                int p = atomicAdd(&cnt[b], 1);
                if (p < CAP) {
                    cval[b * CAP + p] = vals[s];
                    cidx[b * CAP + p] = base_n + 4 * i + s;
                }
            }
        }
    }
}

// --- Pass 4: exact rank-(R-1) element under (value desc, index asc) ---
__global__ void refine_kernel(const int* __restrict__ tbR, const int* __restrict__ cnt,
                              const float* __restrict__ cval, const int* __restrict__ cidx,
                              float* __restrict__ T, int* __restrict__ ncut) {
    const int b = blockIdx.x;
    const int R = tbR[2 * b + 1];
    int M = cnt[b];
    bool ovf = (M > CAP);
    if (M > CAP) M = CAP;
    __shared__ float sv[CAP];
    __shared__ int   si[CAP];
    for (int i = threadIdx.x; i < M; i += 256) {
        sv[i] = cval[b * CAP + i];
        si[i] = cidx[b * CAP + i];
    }
    __syncthreads();
    if (ovf || R > M || R < 1) {   // statistically unreachable fallback
        if (threadIdx.x == 0) { T[b] = (float)tbR[2 * b] / (float)NB; ncut[b] = 0x7fffffff; }
        return;
    }
    for (int i = threadIdx.x; i < M; i += 256) {
        float vi = sv[i]; int ii = si[i];
        int r = 0;
        for (int j = 0; j < M; j++) {
            float vj = sv[j];
            r += (vj > vi) || (vj == vi && si[j] < ii);
        }
        if (r == R - 1) { T[b] = vi; ncut[b] = ii; }  // unique rank -> one writer
    }
}

__device__ __forceinline__ float token_loss(float d0, float d1, float u0, float u1,
                                            bool sel) {
    float g0 = -__logf(-__logf(u0));
    float g1 = -__logf(-__logf(u1));
    float dd = (d0 + g0) - (d1 + g1);
    float l  = __logf(1.f + __expf(-fabsf(dd)));
    float lp0 = (dd >= 0.f) ? -l      : dd - l;
    float lp1 = (dd >= 0.f) ? -l - dd : -l;
    lp0 = fmaxf(lp0, -100.f); lp1 = fmaxf(lp1, -100.f);
    return sel ? -lp0 : -lp1;
}

// --- Pass 5: fused loss, 16 tokens/thread, nontemporal streaming of ds/u ---
__global__ void loss_kernel(const float* __restrict__ ds, const float* __restrict__ u,
                            const float* __restrict__ smap, const float* __restrict__ T,
                            const int* __restrict__ ncut, float* __restrict__ partials) {
    int tid = blockIdx.x * blockDim.x + threadIdx.x;  // one thread = 16 tokens
    int b   = tid >> 14;             // NTOK/16 = 16384 threads per batch
    int p16 = tid & 16383;
    const floatx4* ds4 = (const floatx4*)(ds + (size_t)b * NTOK * 2);
    const floatx4* u4  = (const floatx4*)(u  + (size_t)b * NTOK * 2);
    const float4*  s4  = (const float4*)(smap + (size_t)b * NTOK);

    floatx4 dv[8], uv[8];
    float4  sm[4];
#pragma unroll
    for (int j = 0; j < 8; j++) dv[j] = __builtin_nontemporal_load(&ds4[8 * p16 + j]);
#pragma unroll
    for (int j = 0; j < 8; j++) uv[j] = __builtin_nontemporal_load(&u4[8 * p16 + j]);
#pragma unroll
    for (int j = 0; j < 4; j++) sm[j] = s4[4 * p16 + j];

    const float Tb = T[b];
    const int   nc = ncut[b];
    const int   n0 = p16 << 4;
    const float* smf = (const float*)sm;

    float acc = 0.f;
#pragma unroll
    for (int j = 0; j < 8; j++) {
        float v0 = smf[2 * j], v1 = smf[2 * j + 1];
        bool sel0 = (v0 > Tb) || (v0 == Tb && (n0 + 2 * j)     <= nc);
        bool sel1 = (v1 > Tb) || (v1 == Tb && (n0 + 2 * j + 1) <= nc);
        acc += token_loss(dv[j].x, dv[j].y, uv[j].x, uv[j].y, sel0)
             + token_loss(dv[j].z, dv[j].w, uv[j].z, uv[j].w, sel1);
    }

    for (int off = 32; off > 0; off >>= 1) acc += __shfl_down(acc, off, 64);
    __shared__ float red[4];
    int lane = threadIdx.x & 63, wv = threadIdx.x >> 6;
    if (lane == 0) red[wv] = acc;
    __syncthreads();
    if (threadIdx.x == 0)
        partials[blockIdx.x] = red[0] + red[1] + red[2] + red[3];
}

// --- Pass 6: reduce partials into out[0] ---
__global__ void reduce_kernel(const float* __restrict__ partials, float* __restrict__ out) {
    float acc = 0.f;
    for (int i = threadIdx.x; i < LOSS_BLOCKS; i += blockDim.x) acc += partials[i];
    for (int off = 32; off > 0; off >>= 1) acc += __shfl_down(acc, off, 64);
    __shared__ float red[16];
    int lane = threadIdx.x & 63, wv = threadIdx.x >> 6;
    if (lane == 0) red[wv] = acc;
    __syncthreads();
    if (threadIdx.x == 0) {
        float s = 0.f;
        for (int w = 0; w < (int)(blockDim.x >> 6); w++) s += red[w];
        out[0] = s;
    }
}

extern "C" void kernel_launch(void* const* d_in, const int* in_sizes, int n_in,
                              void* d_out, int out_size, void* d_ws, size_t ws_size,
                              hipStream_t stream) {
    const float* ds   = (const float*)d_in[0];   // [B, N, 2]
    const float* smap = (const float*)d_in[1];   // [B, 1, H, W] == [B, N]
    const float* u    = (const float*)d_in[2];   // [B, N, 2]
    const int*   kptr = (const int*)d_in[3];     // scalar K

    // workspace layout
    int*   hist = (int*)d_ws;                    // BATCH*NB per-batch histogram
    int*   cnt  = hist + BATCH * NB;             // BATCH
    int*   tbR  = cnt + BATCH;                   // 2*BATCH
    float* T    = (float*)(tbR + 2 * BATCH);     // BATCH
    int*   ncut = (int*)(T + BATCH);             // BATCH
    float* cval = (float*)(ncut + BATCH);        // BATCH*CAP
    int*   cidx = (int*)(cval + BATCH * CAP);    // BATCH*CAP
    float* partials = (float*)(cidx + BATCH * CAP);  // LOSS_BLOCKS

    hipMemsetAsync(hist, 0, (size_t)(BATCH * NB) * sizeof(int), stream);
    hist_kernel<<<HB, 256, 0, stream>>>(smap, hist);
    select_kernel<<<BATCH, 1024, 0, stream>>>(hist, kptr, tbR, cnt);
    collect_kernel<<<HB, 256, 0, stream>>>(smap, tbR, cnt, cval, cidx);
    refine_kernel<<<BATCH, 256, 0, stream>>>(tbR, cnt, cval, cidx, T, ncut);
    loss_kernel<<<LOSS_BLOCKS, 256, 0, stream>>>(ds, u, smap, T, ncut, partials);
    reduce_kernel<<<1, 1024, 0, stream>>>(partials, (float*)d_out);
}